// Round 4
// baseline (668.146 us; speedup 1.0000x reference)
//
#include <hip/hip_runtime.h>
#include <hip/hip_bf16.h>
#include <cstdint>
#include <cstddef>

typedef unsigned short u16;

__device__ __forceinline__ float bf2f(u16 u) {
    return __uint_as_float(((unsigned int)u) << 16);
}
__device__ __forceinline__ u16 f2bf(float f) {
    unsigned int b = __float_as_uint(f);
    unsigned int r = b + 0x7FFFu + ((b >> 16) & 1u);   // round-to-nearest-even
    return (u16)(r >> 16);
}

// ---------------- graph preprocessing ----------------

__global__ void k_deg(const int* __restrict__ dst, int E, int* __restrict__ deg) {
    int e = blockIdx.x * blockDim.x + threadIdx.x;
    if (e < E) atomicAdd(&deg[dst[e]], 1);
}

__global__ void k_dinv(const int* __restrict__ deg, float* __restrict__ dinv, int N) {
    int i = blockIdx.x * blockDim.x + threadIdx.x;
    if (i < N) dinv[i] = rsqrtf((float)(deg[i] + 1));   // +1 = self loop
}

// exclusive scan of deg, blockwise; writes to offs1 (= offsX+1)
__global__ void k_scan1(const int* __restrict__ deg, int* __restrict__ offs1,
                        int* __restrict__ bsum, int N) {
    __shared__ int sh[256];
    int i = blockIdx.x * 256 + threadIdx.x;
    int v = (i < N) ? deg[i] : 0;
    sh[threadIdx.x] = v;
    __syncthreads();
#pragma unroll
    for (int o = 1; o < 256; o <<= 1) {
        int t = (threadIdx.x >= o) ? sh[threadIdx.x - o] : 0;
        __syncthreads();
        sh[threadIdx.x] += t;
        __syncthreads();
    }
    if (i < N) offs1[i] = sh[threadIdx.x] - v;          // exclusive within block
    if (threadIdx.x == 255) bsum[blockIdx.x] = sh[255];
}

__global__ void k_scan2(int* __restrict__ bsum, int nb) {
    __shared__ int sh[1024];
    int t = threadIdx.x;
    sh[t] = (t < nb) ? bsum[t] : 0;
    __syncthreads();
    if (t == 0) {
        int acc = 0;
        for (int i = 0; i < nb; ++i) { int x = sh[i]; sh[i] = acc; acc += x; }
    }
    __syncthreads();
    if (t < nb) bsum[t] = sh[t];
}

__global__ void k_scan3(int* __restrict__ offs1, const int* __restrict__ bsum, int N) {
    int i = blockIdx.x * 256 + threadIdx.x;
    if (i < N) offs1[i] += bsum[blockIdx.x];
}

// after fill, offs1[d] = end of d's slot; start of d = offs1[d-1] = offsX[d]
__global__ void k_fill(const int* __restrict__ ei, int E,
                       int* __restrict__ offs1, int* __restrict__ adj) {
    int e = blockIdx.x * blockDim.x + threadIdx.x;
    if (e >= E) return;
    int s = ei[e], d = ei[E + e];
    int pos = atomicAdd(&offs1[d], 1);
    adj[pos] = s;
}

// ---------------- compute kernels ----------------

// Yb[row] = bf16( (BN? relu(bn(X[row])) : X[row]) @ W * dinv[row] )
// One wave per row: x-row via wave-uniform scalar loads; lane j holds W[:,j].
template <bool BN>
__global__ __launch_bounds__(256) void k_gemm64(
        const float* __restrict__ X, const float* __restrict__ W,
        const float* __restrict__ dinv, const float* __restrict__ sc,
        u16* __restrict__ Yb, int nrows) {
    int lane = threadIdx.x & 63;
    int wid  = (blockIdx.x * blockDim.x + threadIdx.x) >> 6;
    int nw   = (gridDim.x * blockDim.x) >> 6;
    float w[64];
#pragma unroll
    for (int k = 0; k < 64; ++k) w[k] = W[k * 64 + lane];
    for (int row = wid; row < nrows; row += nw) {
        int ur = __builtin_amdgcn_readfirstlane(row);
        const float* xr = X + (size_t)ur * 64;
        float a0 = 0.f, a1 = 0.f, a2 = 0.f, a3 = 0.f;
#pragma unroll
        for (int k = 0; k < 64; k += 4) {
            float x0 = xr[k + 0], x1 = xr[k + 1], x2 = xr[k + 2], x3 = xr[k + 3];
            if (BN) {
                x0 = fmaxf(fmaf(x0, sc[k + 0], sc[64 + k + 0]), 0.f);
                x1 = fmaxf(fmaf(x1, sc[k + 1], sc[64 + k + 1]), 0.f);
                x2 = fmaxf(fmaf(x2, sc[k + 2], sc[64 + k + 2]), 0.f);
                x3 = fmaxf(fmaf(x3, sc[k + 3], sc[64 + k + 3]), 0.f);
            }
            a0 = fmaf(x0, w[k + 0], a0);
            a1 = fmaf(x1, w[k + 1], a1);
            a2 = fmaf(x2, w[k + 2], a2);
            a3 = fmaf(x3, w[k + 3], a3);
        }
        float acc = ((a0 + a1) + (a2 + a3)) * dinv[ur];
        Yb[(size_t)ur * 64 + lane] = f2bf(acc);
    }
}

// out[d] = dinv[d] * (HA[d] + sum_{s in adj(d)} HA[s]); HA (bf16) has dinv[s] folded.
// 8 adjacency ids per uniform s_load, 8 independent HA loads, masked add.
// Fused per-feature sum/sumsq into st[0..63]/st[64..127].
__global__ __launch_bounds__(256) void k_gather(
        const u16* __restrict__ HA, const int* __restrict__ offsX,
        const int* __restrict__ adj, const float* __restrict__ dinv,
        float* __restrict__ out, float* __restrict__ st, int N) {
    int lane = threadIdx.x & 63;
    int wid  = (blockIdx.x * blockDim.x + threadIdx.x) >> 6;
    int nw   = (gridDim.x * blockDim.x) >> 6;
    float s_ = 0.f, sq_ = 0.f;
    for (int row = wid; row < N; row += nw) {
        int ur    = __builtin_amdgcn_readfirstlane(row);
        int start = offsX[ur];
        int end   = offsX[ur + 1];
        float acc = bf2f(HA[(size_t)ur * 64 + lane]);   // self loop
        for (int base = start; base < end; base += 8) {
            int m = end - base;                          // wave-uniform, >= 1
            const int* ap = adj + base;
            int e0 = ap[0], e1 = ap[1], e2 = ap[2], e3 = ap[3];
            int e4 = ap[4], e5 = ap[5], e6 = ap[6], e7 = ap[7];
            float v0 = bf2f(HA[(size_t)e0 * 64 + lane]);
            float v1 = bf2f(HA[(size_t)e1 * 64 + lane]);
            float v2 = bf2f(HA[(size_t)e2 * 64 + lane]);
            float v3 = bf2f(HA[(size_t)e3 * 64 + lane]);
            float v4 = bf2f(HA[(size_t)e4 * 64 + lane]);
            float v5 = bf2f(HA[(size_t)e5 * 64 + lane]);
            float v6 = bf2f(HA[(size_t)e6 * 64 + lane]);
            float v7 = bf2f(HA[(size_t)e7 * 64 + lane]);
            acc += v0;
            acc += (m > 1) ? v1 : 0.f;
            acc += (m > 2) ? v2 : 0.f;
            acc += (m > 3) ? v3 : 0.f;
            acc += (m > 4) ? v4 : 0.f;
            acc += (m > 5) ? v5 : 0.f;
            acc += (m > 6) ? v6 : 0.f;
            acc += (m > 7) ? v7 : 0.f;
        }
        float v = acc * dinv[ur];
        out[(size_t)ur * 64 + lane] = v;
        s_ += v; sq_ += v * v;
    }
    __shared__ float ls[4][64], lq[4][64];
    int grp = threadIdx.x >> 6;
    ls[grp][lane] = s_; lq[grp][lane] = sq_;
    __syncthreads();
    if (grp == 0) {
        s_  = ls[0][lane] + ls[1][lane] + ls[2][lane] + ls[3][lane];
        sq_ = lq[0][lane] + lq[1][lane] + lq[2][lane] + lq[3][lane];
        unsafeAtomicAdd(&st[lane], s_);
        unsafeAtomicAdd(&st[64 + lane], sq_);
    }
}

// sc[f]=g*rsqrt(var+eps); sc[64+f]=be-mean*scale (conv bias cancels in BN)
__global__ void k_mkscale(const float* __restrict__ st, const float* __restrict__ g,
                          const float* __restrict__ be, int nrows, float* __restrict__ sc) {
    int f = threadIdx.x;
    if (f >= 64) return;
    float invn = 1.f / (float)nrows;
    float m   = st[f] * invn;
    float var = st[64 + f] * invn - m * m;
    float scale = g[f] * rsqrtf(var + 1e-5f);
    sc[f]      = scale;
    sc[64 + f] = be[f] - m * scale;
}

// segmented pool: one wave per 64 contiguous rows (batch sorted).
// v = relu(bn2(r2)) + relu(bn1(r1)); psum[batch] += v, one atomic per segment.
__global__ void k_pool(const float* __restrict__ r2, const float* __restrict__ sc2,
                       const float* __restrict__ r1, const float* __restrict__ sc1,
                       const int* __restrict__ batch, float* __restrict__ psum, int N) {
    int lane = threadIdx.x & 63;
    int wv   = (blockIdx.x * blockDim.x + threadIdx.x) >> 6;
    int r0   = wv * 64;
    if (r0 >= N) return;
    int rend = min(r0 + 64, N);
    int bv = (r0 + lane < N) ? batch[r0 + lane] : -1;
    float s2a = sc2[lane], s2b = sc2[64 + lane];
    float s1a = sc1[lane], s1b = sc1[64 + lane];
    float acc = 0.f;
    int cur = __shfl(bv, 0, 64);
    for (int r = r0; r < rend; ++r) {
        int b = __shfl(bv, r - r0, 64);
        if (b != cur) {
            unsafeAtomicAdd(&psum[(size_t)cur * 64 + lane], acc);
            acc = 0.f; cur = b;
        }
        float v2 = fmaxf(fmaf(r2[(size_t)r * 64 + lane], s2a, s2b), 0.f);
        float v1 = fmaxf(fmaf(r1[(size_t)r * 64 + lane], s1a, s1b), 0.f);
        acc += v1 + v2;
    }
    unsafeAtomicAdd(&psum[(size_t)cur * 64 + lane], acc);
}

// cnt[g] via binary search over sorted batch
__global__ void k_cnt(const int* __restrict__ batch, int N, float* __restrict__ cnt, int G) {
    int g = blockIdx.x * blockDim.x + threadIdx.x;
    if (g >= G) return;
    int lo = 0, hi = N;
    while (lo < hi) { int mid = (lo + hi) >> 1; if (batch[mid] < g) lo = mid + 1; else hi = mid; }
    int lb = lo;
    hi = N;
    while (lo < hi) { int mid = (lo + hi) >> 1; if (batch[mid] < g + 1) lo = mid + 1; else hi = mid; }
    cnt[g] = (float)(lo - lb);
}

// one thread per graph: mean-pool -> fc(64->32) relu -> fc(32->10) -> log_softmax
__global__ void k_head(const float* __restrict__ psum, const float* __restrict__ cnt,
                       const float* __restrict__ lw1, const float* __restrict__ lb1,
                       const float* __restrict__ lw2, const float* __restrict__ lb2,
                       float* __restrict__ out, int G) {
    int g = blockIdx.x * blockDim.x + threadIdx.x;
    if (g >= G) return;
    float inv = 1.f / fmaxf(cnt[g], 1.f);
    float p[64];
#pragma unroll
    for (int f = 0; f < 64; ++f) p[f] = psum[(size_t)g * 64 + f] * inv;
    float z[32];
#pragma unroll
    for (int j = 0; j < 32; ++j) {
        float a = lb1[j];
#pragma unroll
        for (int f = 0; f < 64; ++f) a = fmaf(p[f], lw1[f * 32 + j], a);
        z[j] = fmaxf(a, 0.f);
    }
    float lg[10];
    float mx = -1e30f;
#pragma unroll
    for (int c = 0; c < 10; ++c) {
        float a = lb2[c];
#pragma unroll
        for (int j = 0; j < 32; ++j) a = fmaf(z[j], lw2[j * 10 + c], a);
        lg[c] = a;
        mx = fmaxf(mx, a);
    }
    float se = 0.f;
#pragma unroll
    for (int c = 0; c < 10; ++c) se += expf(lg[c] - mx);
    float lse = logf(se) + mx;
#pragma unroll
    for (int c = 0; c < 10; ++c) out[(size_t)g * 10 + c] = lg[c] - lse;
}

// ---------------- launch ----------------

extern "C" void kernel_launch(void* const* d_in, const int* in_sizes, int n_in,
                              void* d_out, int out_size, void* d_ws, size_t ws_size,
                              hipStream_t stream) {
    const float* x    = (const float*)d_in[0];
    const int*   ei   = (const int*)d_in[1];     // [2,E]
    const int*   batch= (const int*)d_in[2];
    const float* W1   = (const float*)d_in[3];
    // d_in[4] = b1 : cancels in BN
    const float* g1   = (const float*)d_in[5];
    const float* be1  = (const float*)d_in[6];
    const float* W2   = (const float*)d_in[7];
    // d_in[8] = b2 : cancels in BN
    const float* g2   = (const float*)d_in[9];
    const float* be2  = (const float*)d_in[10];
    const float* lw1  = (const float*)d_in[11];
    const float* lb1  = (const float*)d_in[12];
    const float* lw2  = (const float*)d_in[13];
    const float* lb2  = (const float*)d_in[14];
    float* out = (float*)d_out;

    const int N = in_sizes[2];
    const int E = in_sizes[1] / 2;
    const int C = 10;
    const int G = out_size / C;
    const int NB = (N + 255) / 256;              // scan blocks (<=1024)

    char* w = (char*)d_ws;
    int*   deg  = (int*)w;      w += (size_t)N * 4;
    int*   offsX= (int*)w;      w += (size_t)(N + 1) * 4;  // offsX[0]=0; offs1=offsX+1
    int*   adj  = (int*)w;      w += (size_t)(E + 8) * 4;  // +8 pad (zeroed) for batch loads
    int*   bsum = (int*)w;      w += 1024 * 4;
    float* dinv = (float*)w;    w += (size_t)N * 4;
    u16*   HAbf = (u16*)w;      w += (size_t)N * 64 * 2;   // bf16 transform out (reused L2)
    float* R1   = (float*)w;    w += (size_t)N * 64 * 4;   // raw agg1
    float* B2   = (float*)w;    w += (size_t)N * 64 * 4;   // raw agg2
    float* st1  = (float*)w;    w += 128 * 4;
    float* sc1  = (float*)w;    w += 128 * 4;
    float* st2  = (float*)w;    w += 128 * 4;
    float* sc2  = (float*)w;    w += 128 * 4;
    float* psum = (float*)w;    w += (size_t)G * 64 * 4;
    float* cnt  = (float*)w;    w += (size_t)G * 4;
    int* offs1 = offsX + 1;

    hipMemsetAsync(deg,   0, (size_t)N * 4, stream);
    hipMemsetAsync(offsX, 0, 4, stream);
    hipMemsetAsync(adj + E, 0, 8 * 4, stream);
    hipMemsetAsync(st1,   0, 128 * 4, stream);
    hipMemsetAsync(st2,   0, 128 * 4, stream);
    hipMemsetAsync(psum,  0, (size_t)G * 64 * 4, stream);

    // graph preprocessing: deg -> dinv, CSR(offsX, adj)
    k_deg  <<<(E + 255) / 256, 256, 0, stream>>>(ei + E, E, deg);
    k_dinv <<<(N + 255) / 256, 256, 0, stream>>>(deg, dinv, N);
    k_scan1<<<NB, 256, 0, stream>>>(deg, offs1, bsum, N);
    k_scan2<<<1, 1024, 0, stream>>>(bsum, NB);
    k_scan3<<<NB, 256, 0, stream>>>(offs1, bsum, N);
    k_fill <<<(E + 255) / 256, 256, 0, stream>>>(ei, E, offs1, adj);
    k_cnt  <<<(G + 255) / 256, 256, 0, stream>>>(batch, N, cnt, G);

    // ---- layer 1 ----
    k_gemm64<false><<<2048, 256, 0, stream>>>(x, W1, dinv, nullptr, HAbf, N);
    k_gather <<<2048, 256, 0, stream>>>(HAbf, offsX, adj, dinv, R1, st1, N);
    k_mkscale<<<1, 64, 0, stream>>>(st1, g1, be1, N, sc1);

    // ---- layer 2 (bn1+relu fused into gemm load; HAbf reused) ----
    k_gemm64<true><<<2048, 256, 0, stream>>>(R1, W2, dinv, sc1, HAbf, N);
    k_gather <<<2048, 256, 0, stream>>>(HAbf, offsX, adj, dinv, B2, st2, N);
    k_mkscale<<<1, 64, 0, stream>>>(st2, g2, be2, N, sc2);

    // fused bn2+relu + recomputed bn1+relu residual + segmented mean-pool
    {
        int waves = (N + 63) / 64;
        int blocks = (waves + 3) / 4;
        k_pool<<<blocks, 256, 0, stream>>>(B2, sc2, R1, sc1, batch, psum, N);
    }

    // head
    k_head<<<(G + 255) / 256, 256, 0, stream>>>(psum, cnt, lw1, lb1, lw2, lb2, out, G);
}

// Round 5
// 563.387 us; speedup vs baseline: 1.1859x; 1.1859x over previous
//
#include <hip/hip_runtime.h>
#include <hip/hip_bf16.h>
#include <cstdint>
#include <cstddef>

typedef unsigned short u16;

__device__ __forceinline__ float bf2f(u16 u) {
    return __uint_as_float(((unsigned int)u) << 16);
}
__device__ __forceinline__ unsigned int f2bf(float f) {
    unsigned int b = __float_as_uint(f);
    unsigned int r = b + 0x7FFFu + ((b >> 16) & 1u);   // round-to-nearest-even
    return r >> 16;
}

// ---------------- graph preprocessing ----------------

__global__ void k_deg(const int* __restrict__ dst, int E, int* __restrict__ deg) {
    int e = blockIdx.x * blockDim.x + threadIdx.x;
    if (e < E) atomicAdd(&deg[dst[e]], 1);
}

__global__ void k_dinv(const int* __restrict__ deg, float* __restrict__ dinv, int N) {
    int i = blockIdx.x * blockDim.x + threadIdx.x;
    if (i < N) dinv[i] = rsqrtf((float)(deg[i] + 1));   // +1 = self loop
}

// exclusive scan of deg, blockwise; writes to offs1 (= offsX+1)
__global__ void k_scan1(const int* __restrict__ deg, int* __restrict__ offs1,
                        int* __restrict__ bsum, int N) {
    __shared__ int sh[256];
    int i = blockIdx.x * 256 + threadIdx.x;
    int v = (i < N) ? deg[i] : 0;
    sh[threadIdx.x] = v;
    __syncthreads();
#pragma unroll
    for (int o = 1; o < 256; o <<= 1) {
        int t = (threadIdx.x >= o) ? sh[threadIdx.x - o] : 0;
        __syncthreads();
        sh[threadIdx.x] += t;
        __syncthreads();
    }
    if (i < N) offs1[i] = sh[threadIdx.x] - v;          // exclusive within block
    if (threadIdx.x == 255) bsum[blockIdx.x] = sh[255];
}

__global__ void k_scan2(int* __restrict__ bsum, int nb) {
    __shared__ int sh[1024];
    int t = threadIdx.x;
    sh[t] = (t < nb) ? bsum[t] : 0;
    __syncthreads();
    if (t == 0) {
        int acc = 0;
        for (int i = 0; i < nb; ++i) { int x = sh[i]; sh[i] = acc; acc += x; }
    }
    __syncthreads();
    if (t < nb) bsum[t] = sh[t];
}

__global__ void k_scan3(int* __restrict__ offs1, const int* __restrict__ bsum, int N) {
    int i = blockIdx.x * 256 + threadIdx.x;
    if (i < N) offs1[i] += bsum[blockIdx.x];
}

// after fill, offs1[d] = end of d's slot; start of d = offs1[d-1] = offsX[d]
__global__ void k_fill(const int* __restrict__ ei, int E,
                       int* __restrict__ offs1, int* __restrict__ adj) {
    int e = blockIdx.x * blockDim.x + threadIdx.x;
    if (e >= E) return;
    int s = ei[e], d = ei[E + e];
    int pos = atomicAdd(&offs1[d], 1);
    adj[pos] = s;
}

// ---------------- compute kernels ----------------

// Yb[row] = bf16( Xrow @ W * dinv[row] ).
// One wave per row. X row read via wave-uniform scalar loads (fp32, or bf16
// with SALU unpack); lane j holds W[:,j] in 64 VGPRs (launch_bounds(.,1)
// unlocks the register budget). Inner loop = 64 pure VALU FMAs.
template <bool XBF16>
__global__ __launch_bounds__(256, 1) void k_gemm64(
        const void* __restrict__ Xv, const float* __restrict__ W,
        const float* __restrict__ dinv, u16* __restrict__ Yb, int nrows) {
    int lane = threadIdx.x & 63;
    int wid  = (blockIdx.x * blockDim.x + threadIdx.x) >> 6;
    int nw   = (gridDim.x * blockDim.x) >> 6;
    float w[64];
#pragma unroll
    for (int k = 0; k < 64; ++k) w[k] = W[k * 64 + lane];
    for (int row = wid; row < nrows; row += nw) {
        int ur = __builtin_amdgcn_readfirstlane(row);
        float a0 = 0.f, a1 = 0.f, a2 = 0.f, a3 = 0.f;
        if constexpr (XBF16) {
            const unsigned int* xr = (const unsigned int*)Xv + (size_t)ur * 32;
#pragma unroll
            for (int k2 = 0; k2 < 32; k2 += 2) {
                unsigned int d0 = xr[k2], d1 = xr[k2 + 1];
                float x0 = __uint_as_float(d0 << 16);
                float x1 = __uint_as_float(d0 & 0xFFFF0000u);
                float x2 = __uint_as_float(d1 << 16);
                float x3 = __uint_as_float(d1 & 0xFFFF0000u);
                a0 = fmaf(x0, w[2 * k2 + 0], a0);
                a1 = fmaf(x1, w[2 * k2 + 1], a1);
                a2 = fmaf(x2, w[2 * k2 + 2], a2);
                a3 = fmaf(x3, w[2 * k2 + 3], a3);
            }
        } else {
            const float* xr = (const float*)Xv + (size_t)ur * 64;
#pragma unroll
            for (int k = 0; k < 64; k += 4) {
                a0 = fmaf(xr[k + 0], w[k + 0], a0);
                a1 = fmaf(xr[k + 1], w[k + 1], a1);
                a2 = fmaf(xr[k + 2], w[k + 2], a2);
                a3 = fmaf(xr[k + 3], w[k + 3], a3);
            }
        }
        float acc = ((a0 + a1) + (a2 + a3)) * dinv[ur];
        Yb[(size_t)ur * 64 + lane] = (u16)f2bf(acc);
    }
}

// out[d] = dinv[d] * (HA[d] + sum_{s in adj(d)} HA[s]); HA (bf16) has dinv[s] folded.
// 8 adjacency ids per uniform s_load, 8 independent HA loads, masked add.
// Fused per-feature sum/sumsq into st[0..63]/st[64..127].
__global__ __launch_bounds__(256) void k_gather(
        const u16* __restrict__ HA, const int* __restrict__ offsX,
        const int* __restrict__ adj, const float* __restrict__ dinv,
        float* __restrict__ out, float* __restrict__ st, int N) {
    int lane = threadIdx.x & 63;
    int wid  = (blockIdx.x * blockDim.x + threadIdx.x) >> 6;
    int nw   = (gridDim.x * blockDim.x) >> 6;
    float s_ = 0.f, sq_ = 0.f;
    for (int row = wid; row < N; row += nw) {
        int ur    = __builtin_amdgcn_readfirstlane(row);
        int start = offsX[ur];
        int end   = offsX[ur + 1];
        float acc = bf2f(HA[(size_t)ur * 64 + lane]);   // self loop
        for (int base = start; base < end; base += 8) {
            int m = end - base;                          // wave-uniform, >= 1
            const int* ap = adj + base;
            int e0 = ap[0], e1 = ap[1], e2 = ap[2], e3 = ap[3];
            int e4 = ap[4], e5 = ap[5], e6 = ap[6], e7 = ap[7];
            float v0 = bf2f(HA[(size_t)e0 * 64 + lane]);
            float v1 = bf2f(HA[(size_t)e1 * 64 + lane]);
            float v2 = bf2f(HA[(size_t)e2 * 64 + lane]);
            float v3 = bf2f(HA[(size_t)e3 * 64 + lane]);
            float v4 = bf2f(HA[(size_t)e4 * 64 + lane]);
            float v5 = bf2f(HA[(size_t)e5 * 64 + lane]);
            float v6 = bf2f(HA[(size_t)e6 * 64 + lane]);
            float v7 = bf2f(HA[(size_t)e7 * 64 + lane]);
            acc += v0;
            acc += (m > 1) ? v1 : 0.f;
            acc += (m > 2) ? v2 : 0.f;
            acc += (m > 3) ? v3 : 0.f;
            acc += (m > 4) ? v4 : 0.f;
            acc += (m > 5) ? v5 : 0.f;
            acc += (m > 6) ? v6 : 0.f;
            acc += (m > 7) ? v7 : 0.f;
        }
        float v = acc * dinv[ur];
        out[(size_t)ur * 64 + lane] = v;
        s_ += v; sq_ += v * v;
    }
    __shared__ float ls[4][64], lq[4][64];
    int grp = threadIdx.x >> 6;
    ls[grp][lane] = s_; lq[grp][lane] = sq_;
    __syncthreads();
    if (grp == 0) {
        s_  = ls[0][lane] + ls[1][lane] + ls[2][lane] + ls[3][lane];
        sq_ = lq[0][lane] + lq[1][lane] + lq[2][lane] + lq[3][lane];
        unsafeAtomicAdd(&st[lane], s_);
        unsafeAtomicAdd(&st[64 + lane], sq_);
    }
}

// sc[f]=g*rsqrt(var+eps); sc[64+f]=be-mean*scale (conv bias cancels in BN)
__global__ void k_mkscale(const float* __restrict__ st, const float* __restrict__ g,
                          const float* __restrict__ be, int nrows, float* __restrict__ sc) {
    int f = threadIdx.x;
    if (f >= 64) return;
    float invn = 1.f / (float)nrows;
    float m   = st[f] * invn;
    float var = st[64 + f] * invn - m * m;
    float scale = g[f] * rsqrtf(var + 1e-5f);
    sc[f]      = scale;
    sc[64 + f] = be[f] - m * scale;
}

// elementwise: h1b = bf16(relu(in*scA + scB)), float4 in, 4x bf16 (uint2) out
__global__ void k_bnreluB(const float4* __restrict__ in, const float* __restrict__ sc,
                          uint2* __restrict__ outb, int n4) {
    int i = blockIdx.x * blockDim.x + threadIdx.x;
    int stride = gridDim.x * blockDim.x;
    for (; i < n4; i += stride) {
        int f4 = (i & 15) << 2;
        float4 v = in[i];
        float r0 = fmaxf(fmaf(v.x, sc[f4 + 0], sc[64 + f4 + 0]), 0.f);
        float r1 = fmaxf(fmaf(v.y, sc[f4 + 1], sc[64 + f4 + 1]), 0.f);
        float r2 = fmaxf(fmaf(v.z, sc[f4 + 2], sc[64 + f4 + 2]), 0.f);
        float r3 = fmaxf(fmaf(v.w, sc[f4 + 3], sc[64 + f4 + 3]), 0.f);
        uint2 r;
        r.x = f2bf(r0) | (f2bf(r1) << 16);
        r.y = f2bf(r2) | (f2bf(r3) << 16);
        outb[i] = r;
    }
}

// segmented pool: one wave per 64 contiguous rows (batch sorted).
// v = relu(bn2(r2)) + h1b; psum[batch] += v, one atomic per segment.
__global__ void k_pool(const float* __restrict__ r2, const float* __restrict__ sc2,
                       const u16* __restrict__ h1b, const int* __restrict__ batch,
                       float* __restrict__ psum, int N) {
    int lane = threadIdx.x & 63;
    int wv   = (blockIdx.x * blockDim.x + threadIdx.x) >> 6;
    int r0   = wv * 64;
    if (r0 >= N) return;
    int rend = min(r0 + 64, N);
    int bv = (r0 + lane < N) ? batch[r0 + lane] : -1;
    float s2a = sc2[lane], s2b = sc2[64 + lane];
    float acc = 0.f;
    int cur = __shfl(bv, 0, 64);
    for (int r = r0; r < rend; ++r) {
        int b = __shfl(bv, r - r0, 64);
        if (b != cur) {
            unsafeAtomicAdd(&psum[(size_t)cur * 64 + lane], acc);
            acc = 0.f; cur = b;
        }
        float v2 = fmaxf(fmaf(r2[(size_t)r * 64 + lane], s2a, s2b), 0.f);
        float v1 = bf2f(h1b[(size_t)r * 64 + lane]);
        acc += v1 + v2;
    }
    unsafeAtomicAdd(&psum[(size_t)cur * 64 + lane], acc);
}

// cnt[g] via binary search over sorted batch
__global__ void k_cnt(const int* __restrict__ batch, int N, float* __restrict__ cnt, int G) {
    int g = blockIdx.x * blockDim.x + threadIdx.x;
    if (g >= G) return;
    int lo = 0, hi = N;
    while (lo < hi) { int mid = (lo + hi) >> 1; if (batch[mid] < g) lo = mid + 1; else hi = mid; }
    int lb = lo;
    hi = N;
    while (lo < hi) { int mid = (lo + hi) >> 1; if (batch[mid] < g + 1) lo = mid + 1; else hi = mid; }
    cnt[g] = (float)(lo - lb);
}

// one thread per graph: mean-pool -> fc(64->32) relu -> fc(32->10) -> log_softmax
__global__ void k_head(const float* __restrict__ psum, const float* __restrict__ cnt,
                       const float* __restrict__ lw1, const float* __restrict__ lb1,
                       const float* __restrict__ lw2, const float* __restrict__ lb2,
                       float* __restrict__ out, int G) {
    int g = blockIdx.x * blockDim.x + threadIdx.x;
    if (g >= G) return;
    float inv = 1.f / fmaxf(cnt[g], 1.f);
    float p[64];
#pragma unroll
    for (int f = 0; f < 64; ++f) p[f] = psum[(size_t)g * 64 + f] * inv;
    float z[32];
#pragma unroll
    for (int j = 0; j < 32; ++j) {
        float a = lb1[j];
#pragma unroll
        for (int f = 0; f < 64; ++f) a = fmaf(p[f], lw1[f * 32 + j], a);
        z[j] = fmaxf(a, 0.f);
    }
    float lg[10];
    float mx = -1e30f;
#pragma unroll
    for (int c = 0; c < 10; ++c) {
        float a = lb2[c];
#pragma unroll
        for (int j = 0; j < 32; ++j) a = fmaf(z[j], lw2[j * 10 + c], a);
        lg[c] = a;
        mx = fmaxf(mx, a);
    }
    float se = 0.f;
#pragma unroll
    for (int c = 0; c < 10; ++c) se += expf(lg[c] - mx);
    float lse = logf(se) + mx;
#pragma unroll
    for (int c = 0; c < 10; ++c) out[(size_t)g * 10 + c] = lg[c] - lse;
}

// ---------------- launch ----------------

extern "C" void kernel_launch(void* const* d_in, const int* in_sizes, int n_in,
                              void* d_out, int out_size, void* d_ws, size_t ws_size,
                              hipStream_t stream) {
    const float* x    = (const float*)d_in[0];
    const int*   ei   = (const int*)d_in[1];     // [2,E]
    const int*   batch= (const int*)d_in[2];
    const float* W1   = (const float*)d_in[3];
    // d_in[4] = b1 : cancels in BN
    const float* g1   = (const float*)d_in[5];
    const float* be1  = (const float*)d_in[6];
    const float* W2   = (const float*)d_in[7];
    // d_in[8] = b2 : cancels in BN
    const float* g2   = (const float*)d_in[9];
    const float* be2  = (const float*)d_in[10];
    const float* lw1  = (const float*)d_in[11];
    const float* lb1  = (const float*)d_in[12];
    const float* lw2  = (const float*)d_in[13];
    const float* lb2  = (const float*)d_in[14];
    float* out = (float*)d_out;

    const int N = in_sizes[2];
    const int E = in_sizes[1] / 2;
    const int C = 10;
    const int G = out_size / C;
    const int NB = (N + 255) / 256;              // scan blocks (<=1024)

    char* w = (char*)d_ws;
    int*   deg  = (int*)w;      w += (size_t)N * 4;
    int*   offsX= (int*)w;      w += (size_t)(N + 1) * 4;  // offsX[0]=0; offs1=offsX+1
    int*   adj  = (int*)w;      w += (size_t)(E + 8) * 4;  // +8 pad (zeroed) for batch loads
    int*   bsum = (int*)w;      w += 1024 * 4;
    float* dinv = (float*)w;    w += (size_t)N * 4;
    u16*   HAbf = (u16*)w;      w += (size_t)N * 64 * 2;   // bf16 transform out (t1, then t2)
    u16*   h1b  = (u16*)w;      w += (size_t)N * 64 * 2;   // bf16 relu(bn1(R1))
    float* RB   = (float*)w;    w += (size_t)N * 64 * 4;   // raw agg1, then raw agg2
    float* st1  = (float*)w;    w += 128 * 4;
    float* sc1  = (float*)w;    w += 128 * 4;
    float* st2  = (float*)w;    w += 128 * 4;
    float* sc2  = (float*)w;    w += 128 * 4;
    float* psum = (float*)w;    w += (size_t)G * 64 * 4;
    float* cnt  = (float*)w;    w += (size_t)G * 4;
    int* offs1 = offsX + 1;

    hipMemsetAsync(deg,   0, (size_t)N * 4, stream);
    hipMemsetAsync(offsX, 0, 4, stream);
    hipMemsetAsync(adj + E, 0, 8 * 4, stream);
    hipMemsetAsync(st1,   0, 128 * 4, stream);
    hipMemsetAsync(st2,   0, 128 * 4, stream);
    hipMemsetAsync(psum,  0, (size_t)G * 64 * 4, stream);

    // graph preprocessing: deg -> dinv, CSR(offsX, adj)
    k_deg  <<<(E + 255) / 256, 256, 0, stream>>>(ei + E, E, deg);
    k_dinv <<<(N + 255) / 256, 256, 0, stream>>>(deg, dinv, N);
    k_scan1<<<NB, 256, 0, stream>>>(deg, offs1, bsum, N);
    k_scan2<<<1, 1024, 0, stream>>>(bsum, NB);
    k_scan3<<<NB, 256, 0, stream>>>(offs1, bsum, N);
    k_fill <<<(E + 255) / 256, 256, 0, stream>>>(ei, E, offs1, adj);
    k_cnt  <<<(G + 255) / 256, 256, 0, stream>>>(batch, N, cnt, G);

    // ---- layer 1 ----
    k_gemm64<false><<<2048, 256, 0, stream>>>(x, W1, dinv, HAbf, N);
    k_gather <<<2048, 256, 0, stream>>>(HAbf, offsX, adj, dinv, RB, st1, N);
    k_mkscale<<<1, 64, 0, stream>>>(st1, g1, be1, N, sc1);
    k_bnreluB<<<2048, 256, 0, stream>>>((const float4*)RB, sc1, (uint2*)h1b, N * 16);

    // ---- layer 2 ----
    k_gemm64<true><<<2048, 256, 0, stream>>>(h1b, W2, dinv, HAbf, N);
    k_gather <<<2048, 256, 0, stream>>>(HAbf, offsX, adj, dinv, RB, st2, N);
    k_mkscale<<<1, 64, 0, stream>>>(st2, g2, be2, N, sc2);

    // fused bn2+relu + bf16 h1 residual + segmented mean-pool
    {
        int waves = (N + 63) / 64;
        int blocks = (waves + 3) / 4;
        k_pool<<<blocks, 256, 0, stream>>>(RB, sc2, h1b, batch, psum, N);
    }

    // head
    k_head<<<(G + 255) / 256, 256, 0, stream>>>(psum, cnt, lw1, lb1, lw2, lb2, out, G);
}

// Round 6
// 553.082 us; speedup vs baseline: 1.2080x; 1.0186x over previous
//
#include <hip/hip_runtime.h>
#include <hip/hip_bf16.h>
#include <cstdint>
#include <cstddef>

typedef unsigned short u16;

__device__ __forceinline__ float bf2f(u16 u) {
    return __uint_as_float(((unsigned int)u) << 16);
}
__device__ __forceinline__ unsigned int f2bf(float f) {
    unsigned int b = __float_as_uint(f);
    unsigned int r = b + 0x7FFFu + ((b >> 16) & 1u);   // round-to-nearest-even
    return r >> 16;
}

// ---------------- graph preprocessing ----------------

__global__ void k_deg(const int* __restrict__ dst, int E, int* __restrict__ deg) {
    int e = blockIdx.x * blockDim.x + threadIdx.x;
    if (e < E) atomicAdd(&deg[dst[e]], 1);
}

__global__ void k_dinv(const int* __restrict__ deg, float* __restrict__ dinv, int N) {
    int i = blockIdx.x * blockDim.x + threadIdx.x;
    if (i < N) dinv[i] = rsqrtf((float)(deg[i] + 1));   // +1 = self loop
}

// exclusive scan of deg, blockwise; writes to offs1 (= offsX+1)
__global__ void k_scan1(const int* __restrict__ deg, int* __restrict__ offs1,
                        int* __restrict__ bsum, int N) {
    __shared__ int sh[256];
    int i = blockIdx.x * 256 + threadIdx.x;
    int v = (i < N) ? deg[i] : 0;
    sh[threadIdx.x] = v;
    __syncthreads();
#pragma unroll
    for (int o = 1; o < 256; o <<= 1) {
        int t = (threadIdx.x >= o) ? sh[threadIdx.x - o] : 0;
        __syncthreads();
        sh[threadIdx.x] += t;
        __syncthreads();
    }
    if (i < N) offs1[i] = sh[threadIdx.x] - v;          // exclusive within block
    if (threadIdx.x == 255) bsum[blockIdx.x] = sh[255];
}

__global__ void k_scan2(int* __restrict__ bsum, int nb) {
    __shared__ int sh[1024];
    int t = threadIdx.x;
    sh[t] = (t < nb) ? bsum[t] : 0;
    __syncthreads();
    if (t == 0) {
        int acc = 0;
        for (int i = 0; i < nb; ++i) { int x = sh[i]; sh[i] = acc; acc += x; }
    }
    __syncthreads();
    if (t < nb) bsum[t] = sh[t];
}

__global__ void k_scan3(int* __restrict__ offs1, const int* __restrict__ bsum, int N) {
    int i = blockIdx.x * 256 + threadIdx.x;
    if (i < N) offs1[i] += bsum[blockIdx.x];
}

// after fill, offs1[d] = end of d's slot; start of d = offs1[d-1] = offsX[d]
__global__ void k_fill(const int* __restrict__ ei, int E,
                       int* __restrict__ offs1, int* __restrict__ adj) {
    int e = blockIdx.x * blockDim.x + threadIdx.x;
    if (e >= E) return;
    int s = ei[e], d = ei[E + e];
    int pos = atomicAdd(&offs1[d], 1);
    adj[pos] = s;
}

// ---------------- compute kernels ----------------

// Yb[row] = bf16( Xrow @ W * dinv[row] ).
// One wave per row; X row via wave-uniform scalar loads; lane j holds W[:,j].
template <bool XBF16>
__global__ __launch_bounds__(256, 1) void k_gemm64(
        const void* __restrict__ Xv, const float* __restrict__ W,
        const float* __restrict__ dinv, u16* __restrict__ Yb, int nrows) {
    int lane = threadIdx.x & 63;
    int wid  = (blockIdx.x * blockDim.x + threadIdx.x) >> 6;
    int nw   = (gridDim.x * blockDim.x) >> 6;
    float w[64];
#pragma unroll
    for (int k = 0; k < 64; ++k) w[k] = W[k * 64 + lane];
    for (int row = wid; row < nrows; row += nw) {
        int ur = __builtin_amdgcn_readfirstlane(row);
        float a0 = 0.f, a1 = 0.f, a2 = 0.f, a3 = 0.f;
        if constexpr (XBF16) {
            const unsigned int* xr = (const unsigned int*)Xv + (size_t)ur * 32;
#pragma unroll
            for (int k2 = 0; k2 < 32; k2 += 2) {
                unsigned int d0 = xr[k2], d1 = xr[k2 + 1];
                float x0 = __uint_as_float(d0 << 16);
                float x1 = __uint_as_float(d0 & 0xFFFF0000u);
                float x2 = __uint_as_float(d1 << 16);
                float x3 = __uint_as_float(d1 & 0xFFFF0000u);
                a0 = fmaf(x0, w[2 * k2 + 0], a0);
                a1 = fmaf(x1, w[2 * k2 + 1], a1);
                a2 = fmaf(x2, w[2 * k2 + 2], a2);
                a3 = fmaf(x3, w[2 * k2 + 3], a3);
            }
        } else {
            const float* xr = (const float*)Xv + (size_t)ur * 64;
#pragma unroll
            for (int k = 0; k < 64; k += 4) {
                a0 = fmaf(xr[k + 0], w[k + 0], a0);
                a1 = fmaf(xr[k + 1], w[k + 1], a1);
                a2 = fmaf(xr[k + 2], w[k + 2], a2);
                a3 = fmaf(xr[k + 3], w[k + 3], a3);
            }
        }
        float acc = ((a0 + a1) + (a2 + a3)) * dinv[ur];
        Yb[(size_t)ur * 64 + lane] = (u16)f2bf(acc);
    }
}

// 4-row batched gather: outb[d] = bf16( dinv[d] * (HA[d] + sum_{s in adj(d)} HA[s]) ).
// Per batch of 4 consecutive rows: 5 independent offs s_loads, contiguous CSR
// span processed in 16-edge aligned chunks (1 s_load_dwordx16 + 16 independent
// HA vloads), edges routed to 4 accumulators via uniform-condition masked adds.
// Fused per-feature sum/sumsq (of the rounded values) into st[0..63]/st[64..127].
__global__ __launch_bounds__(256) void k_gather(
        const u16* __restrict__ HA, const int* __restrict__ offsX,
        const int* __restrict__ adj, const float* __restrict__ dinv,
        u16* __restrict__ outb, float* __restrict__ st, int N) {
    int lane = threadIdx.x & 63;
    int wid  = (blockIdx.x * blockDim.x + threadIdx.x) >> 6;
    int nw   = (gridDim.x * blockDim.x) >> 6;
    float s_ = 0.f, sq_ = 0.f;
    int nb4 = (N + 3) >> 2;
    for (int bt = wid; bt < nb4; bt += nw) {
        int r0 = __builtin_amdgcn_readfirstlane(bt << 2);
        int r1 = min(r0 + 1, N - 1);
        int r2 = min(r0 + 2, N - 1);
        int r3 = min(r0 + 3, N - 1);
        int o0 = offsX[r0];
        int o1 = offsX[min(r0 + 1, N)];
        int o2 = offsX[min(r0 + 2, N)];
        int o3 = offsX[min(r0 + 3, N)];
        int o4 = offsX[min(r0 + 4, N)];
        // self loops (independent of offs loads)
        float a0 = bf2f(HA[(size_t)r0 * 64 + lane]);
        float a1 = bf2f(HA[(size_t)r1 * 64 + lane]);
        float a2 = bf2f(HA[(size_t)r2 * 64 + lane]);
        float a3 = bf2f(HA[(size_t)r3 * 64 + lane]);
        int j0 = o0 & ~15;                       // 64B-aligned chunk start
        for (int j = j0; j < o4; j += 16) {
            const int* ap = adj + j;
            int e0 = ap[0],  e1 = ap[1],  e2 = ap[2],  e3 = ap[3];
            int e4 = ap[4],  e5 = ap[5],  e6 = ap[6],  e7 = ap[7];
            int e8 = ap[8],  e9 = ap[9],  e10 = ap[10], e11 = ap[11];
            int e12 = ap[12], e13 = ap[13], e14 = ap[14], e15 = ap[15];
            float v0  = bf2f(HA[(size_t)e0  * 64 + lane]);
            float v1  = bf2f(HA[(size_t)e1  * 64 + lane]);
            float v2  = bf2f(HA[(size_t)e2  * 64 + lane]);
            float v3  = bf2f(HA[(size_t)e3  * 64 + lane]);
            float v4  = bf2f(HA[(size_t)e4  * 64 + lane]);
            float v5  = bf2f(HA[(size_t)e5  * 64 + lane]);
            float v6  = bf2f(HA[(size_t)e6  * 64 + lane]);
            float v7  = bf2f(HA[(size_t)e7  * 64 + lane]);
            float v8  = bf2f(HA[(size_t)e8  * 64 + lane]);
            float v9  = bf2f(HA[(size_t)e9  * 64 + lane]);
            float v10 = bf2f(HA[(size_t)e10 * 64 + lane]);
            float v11 = bf2f(HA[(size_t)e11 * 64 + lane]);
            float v12 = bf2f(HA[(size_t)e12 * 64 + lane]);
            float v13 = bf2f(HA[(size_t)e13 * 64 + lane]);
            float v14 = bf2f(HA[(size_t)e14 * 64 + lane]);
            float v15 = bf2f(HA[(size_t)e15 * 64 + lane]);
#define ACC(K, VK) { int t = j + K;                                    \
            float v = (t >= o0 && t < o4) ? (VK) : 0.f;                \
            a0 += (t < o1) ? v : 0.f;                                  \
            a1 += (t >= o1 && t < o2) ? v : 0.f;                       \
            a2 += (t >= o2 && t < o3) ? v : 0.f;                       \
            a3 += (t >= o3) ? v : 0.f; }
            ACC(0, v0)  ACC(1, v1)  ACC(2, v2)  ACC(3, v3)
            ACC(4, v4)  ACC(5, v5)  ACC(6, v6)  ACC(7, v7)
            ACC(8, v8)  ACC(9, v9)  ACC(10, v10) ACC(11, v11)
            ACC(12, v12) ACC(13, v13) ACC(14, v14) ACC(15, v15)
#undef ACC
        }
        float d0 = dinv[r0], d1 = dinv[r1], d2 = dinv[r2], d3 = dinv[r3];
        {
            u16 u = (u16)f2bf(a0 * d0);
            outb[(size_t)r0 * 64 + lane] = u;
            float vr = bf2f(u); s_ += vr; sq_ += vr * vr;
        }
        if (r0 + 1 < N) {
            u16 u = (u16)f2bf(a1 * d1);
            outb[(size_t)r1 * 64 + lane] = u;
            float vr = bf2f(u); s_ += vr; sq_ += vr * vr;
        }
        if (r0 + 2 < N) {
            u16 u = (u16)f2bf(a2 * d2);
            outb[(size_t)r2 * 64 + lane] = u;
            float vr = bf2f(u); s_ += vr; sq_ += vr * vr;
        }
        if (r0 + 3 < N) {
            u16 u = (u16)f2bf(a3 * d3);
            outb[(size_t)r3 * 64 + lane] = u;
            float vr = bf2f(u); s_ += vr; sq_ += vr * vr;
        }
    }
    __shared__ float ls[4][64], lq[4][64];
    int grp = threadIdx.x >> 6;
    ls[grp][lane] = s_; lq[grp][lane] = sq_;
    __syncthreads();
    if (grp == 0) {
        s_  = ls[0][lane] + ls[1][lane] + ls[2][lane] + ls[3][lane];
        sq_ = lq[0][lane] + lq[1][lane] + lq[2][lane] + lq[3][lane];
        unsafeAtomicAdd(&st[lane], s_);
        unsafeAtomicAdd(&st[64 + lane], sq_);
    }
}

// sc[f]=g*rsqrt(var+eps); sc[64+f]=be-mean*scale (conv bias cancels in BN)
__global__ void k_mkscale(const float* __restrict__ st, const float* __restrict__ g,
                          const float* __restrict__ be, int nrows, float* __restrict__ sc) {
    int f = threadIdx.x;
    if (f >= 64) return;
    float invn = 1.f / (float)nrows;
    float m   = st[f] * invn;
    float var = st[64 + f] * invn - m * m;
    float scale = g[f] * rsqrtf(var + 1e-5f);
    sc[f]      = scale;
    sc[64 + f] = be[f] - m * scale;
}

// elementwise: h1b = bf16(relu(in*scA + scB)); bf16 in (uint2 = 4 elems), bf16 out
__global__ void k_bnreluB(const uint2* __restrict__ inb, const float* __restrict__ sc,
                          uint2* __restrict__ outb, int n4) {
    int i = blockIdx.x * blockDim.x + threadIdx.x;
    int stride = gridDim.x * blockDim.x;
    for (; i < n4; i += stride) {
        int f4 = (i & 15) << 2;
        uint2 p = inb[i];
        float v0 = __uint_as_float(p.x << 16);
        float v1 = __uint_as_float(p.x & 0xFFFF0000u);
        float v2 = __uint_as_float(p.y << 16);
        float v3 = __uint_as_float(p.y & 0xFFFF0000u);
        float r0 = fmaxf(fmaf(v0, sc[f4 + 0], sc[64 + f4 + 0]), 0.f);
        float r1 = fmaxf(fmaf(v1, sc[f4 + 1], sc[64 + f4 + 1]), 0.f);
        float r2 = fmaxf(fmaf(v2, sc[f4 + 2], sc[64 + f4 + 2]), 0.f);
        float r3 = fmaxf(fmaf(v3, sc[f4 + 3], sc[64 + f4 + 3]), 0.f);
        uint2 r;
        r.x = f2bf(r0) | (f2bf(r1) << 16);
        r.y = f2bf(r2) | (f2bf(r3) << 16);
        outb[i] = r;
    }
}

// segmented pool: one wave per 64 contiguous rows (batch sorted).
// v = relu(bn2(r2b)) + h1b; psum[batch] += v, one atomic per segment.
__global__ void k_pool(const u16* __restrict__ r2b, const float* __restrict__ sc2,
                       const u16* __restrict__ h1b, const int* __restrict__ batch,
                       float* __restrict__ psum, int N) {
    int lane = threadIdx.x & 63;
    int wv   = (blockIdx.x * blockDim.x + threadIdx.x) >> 6;
    int r0   = wv * 64;
    if (r0 >= N) return;
    int rend = min(r0 + 64, N);
    int bv = (r0 + lane < N) ? batch[r0 + lane] : -1;
    float s2a = sc2[lane], s2b = sc2[64 + lane];
    float acc = 0.f;
    int cur = __shfl(bv, 0, 64);
    for (int r = r0; r < rend; ++r) {
        int b = __shfl(bv, r - r0, 64);
        if (b != cur) {
            unsafeAtomicAdd(&psum[(size_t)cur * 64 + lane], acc);
            acc = 0.f; cur = b;
        }
        float v2 = fmaxf(fmaf(bf2f(r2b[(size_t)r * 64 + lane]), s2a, s2b), 0.f);
        float v1 = bf2f(h1b[(size_t)r * 64 + lane]);
        acc += v1 + v2;
    }
    unsafeAtomicAdd(&psum[(size_t)cur * 64 + lane], acc);
}

// cnt[g] via binary search over sorted batch
__global__ void k_cnt(const int* __restrict__ batch, int N, float* __restrict__ cnt, int G) {
    int g = blockIdx.x * blockDim.x + threadIdx.x;
    if (g >= G) return;
    int lo = 0, hi = N;
    while (lo < hi) { int mid = (lo + hi) >> 1; if (batch[mid] < g) lo = mid + 1; else hi = mid; }
    int lb = lo;
    hi = N;
    while (lo < hi) { int mid = (lo + hi) >> 1; if (batch[mid] < g + 1) lo = mid + 1; else hi = mid; }
    cnt[g] = (float)(lo - lb);
}

// one thread per graph: mean-pool -> fc(64->32) relu -> fc(32->10) -> log_softmax
__global__ void k_head(const float* __restrict__ psum, const float* __restrict__ cnt,
                       const float* __restrict__ lw1, const float* __restrict__ lb1,
                       const float* __restrict__ lw2, const float* __restrict__ lb2,
                       float* __restrict__ out, int G) {
    int g = blockIdx.x * blockDim.x + threadIdx.x;
    if (g >= G) return;
    float inv = 1.f / fmaxf(cnt[g], 1.f);
    float p[64];
#pragma unroll
    for (int f = 0; f < 64; ++f) p[f] = psum[(size_t)g * 64 + f] * inv;
    float z[32];
#pragma unroll
    for (int j = 0; j < 32; ++j) {
        float a = lb1[j];
#pragma unroll
        for (int f = 0; f < 64; ++f) a = fmaf(p[f], lw1[f * 32 + j], a);
        z[j] = fmaxf(a, 0.f);
    }
    float lg[10];
    float mx = -1e30f;
#pragma unroll
    for (int c = 0; c < 10; ++c) {
        float a = lb2[c];
#pragma unroll
        for (int j = 0; j < 32; ++j) a = fmaf(z[j], lw2[j * 10 + c], a);
        lg[c] = a;
        mx = fmaxf(mx, a);
    }
    float se = 0.f;
#pragma unroll
    for (int c = 0; c < 10; ++c) se += expf(lg[c] - mx);
    float lse = logf(se) + mx;
#pragma unroll
    for (int c = 0; c < 10; ++c) out[(size_t)g * 10 + c] = lg[c] - lse;
}

// ---------------- launch ----------------

extern "C" void kernel_launch(void* const* d_in, const int* in_sizes, int n_in,
                              void* d_out, int out_size, void* d_ws, size_t ws_size,
                              hipStream_t stream) {
    const float* x    = (const float*)d_in[0];
    const int*   ei   = (const int*)d_in[1];     // [2,E]
    const int*   batch= (const int*)d_in[2];
    const float* W1   = (const float*)d_in[3];
    // d_in[4] = b1 : cancels in BN
    const float* g1   = (const float*)d_in[5];
    const float* be1  = (const float*)d_in[6];
    const float* W2   = (const float*)d_in[7];
    // d_in[8] = b2 : cancels in BN
    const float* g2   = (const float*)d_in[9];
    const float* be2  = (const float*)d_in[10];
    const float* lw1  = (const float*)d_in[11];
    const float* lb1  = (const float*)d_in[12];
    const float* lw2  = (const float*)d_in[13];
    const float* lb2  = (const float*)d_in[14];
    float* out = (float*)d_out;

    const int N = in_sizes[2];
    const int E = in_sizes[1] / 2;
    const int C = 10;
    const int G = out_size / C;
    const int NB = (N + 255) / 256;              // scan blocks (<=1024)

    char* w = (char*)d_ws;
    int*   deg  = (int*)w;      w += (size_t)N * 4;
    int*   offsX= (int*)w;      w += (size_t)(N + 1) * 4;  // offsX[0]=0; offs1=offsX+1
    int*   adj  = (int*)w;      w += (size_t)(E + 16) * 4; // +16 pad (zeroed) for chunk loads
    int*   bsum = (int*)w;      w += 1024 * 4;
    float* dinv = (float*)w;    w += (size_t)N * 4;
    u16*   HAbf = (u16*)w;      w += (size_t)N * 64 * 2;   // bf16 transform out (t1, then t2)
    u16*   h1b  = (u16*)w;      w += (size_t)N * 64 * 2;   // bf16 relu(bn1(agg1))
    u16*   Rb   = (u16*)w;      w += (size_t)N * 64 * 2;   // bf16 raw agg1, then raw agg2
    float* st1  = (float*)w;    w += 128 * 4;
    float* sc1  = (float*)w;    w += 128 * 4;
    float* st2  = (float*)w;    w += 128 * 4;
    float* sc2  = (float*)w;    w += 128 * 4;
    float* psum = (float*)w;    w += (size_t)G * 64 * 4;
    float* cnt  = (float*)w;    w += (size_t)G * 4;
    int* offs1 = offsX + 1;

    hipMemsetAsync(deg,   0, (size_t)N * 4, stream);
    hipMemsetAsync(offsX, 0, 4, stream);
    hipMemsetAsync(adj + E, 0, 16 * 4, stream);
    hipMemsetAsync(st1,   0, 128 * 4, stream);
    hipMemsetAsync(st2,   0, 128 * 4, stream);
    hipMemsetAsync(psum,  0, (size_t)G * 64 * 4, stream);

    // graph preprocessing: deg -> dinv, CSR(offsX, adj)
    k_deg  <<<(E + 255) / 256, 256, 0, stream>>>(ei + E, E, deg);
    k_dinv <<<(N + 255) / 256, 256, 0, stream>>>(deg, dinv, N);
    k_scan1<<<NB, 256, 0, stream>>>(deg, offs1, bsum, N);
    k_scan2<<<1, 1024, 0, stream>>>(bsum, NB);
    k_scan3<<<NB, 256, 0, stream>>>(offs1, bsum, N);
    k_fill <<<(E + 255) / 256, 256, 0, stream>>>(ei, E, offs1, adj);
    k_cnt  <<<(G + 255) / 256, 256, 0, stream>>>(batch, N, cnt, G);

    // ---- layer 1 ----
    k_gemm64<false><<<2048, 256, 0, stream>>>(x, W1, dinv, HAbf, N);
    k_gather <<<2048, 256, 0, stream>>>(HAbf, offsX, adj, dinv, Rb, st1, N);
    k_mkscale<<<1, 64, 0, stream>>>(st1, g1, be1, N, sc1);
    k_bnreluB<<<2048, 256, 0, stream>>>((const uint2*)Rb, sc1, (uint2*)h1b, N * 16);

    // ---- layer 2 ----
    k_gemm64<true><<<2048, 256, 0, stream>>>(h1b, W2, dinv, HAbf, N);
    k_gather <<<2048, 256, 0, stream>>>(HAbf, offsX, adj, dinv, Rb, st2, N);
    k_mkscale<<<1, 64, 0, stream>>>(st2, g2, be2, N, sc2);

    // fused bn2+relu + bf16 h1 residual + segmented mean-pool
    {
        int waves = (N + 63) / 64;
        int blocks = (waves + 3) / 4;
        k_pool<<<blocks, 256, 0, stream>>>(Rb, sc2, h1b, batch, psum, N);
    }

    // head
    k_head<<<(G + 255) / 256, 256, 0, stream>>>(psum, cnt, lw1, lb1, lw2, lb2, out, G);
}